// Round 3
// baseline (71.425 us; speedup 1.0000x reference)
//
#include <hip/hip_runtime.h>

#define D_MODEL 2048
#define N_EXP 8
#define TOPK 2
#define TPG 4               // tokens per wave
#define NCHUNK (D_MODEL / 256)  // 8 chunks of 256 elems (64 lanes x float4)

// One wave handles 4 tokens. H is double-buffered in registers (explicit
// prefetch of chunk j+1 while FMA-ing chunk j) to force memory-level
// parallelism; W (64 KB, L2-resident) loaded per chunk, 8 float4/lane.
// VGPR budget: hbuf 32 + w 32 + acc 32 + addr/misc ~ 115 -> 4 waves/SIMD.
__global__ __launch_bounds__(256, 4) void moe_gate_kernel(
    const float* __restrict__ H, const float* __restrict__ W,
    float* __restrict__ out_idx, float* __restrict__ out_prob,
    unsigned int* __restrict__ counts, int n_tokens)
{
    __shared__ unsigned int hist[N_EXP];
    __shared__ float red[4][TPG * N_EXP];  // per-wave logit scratch (512 B)

    const int tid = threadIdx.x;
    if (tid < N_EXP) hist[tid] = 0u;

    const int lane = tid & 63;
    const int wid = tid >> 6;
    const int gwave = blockIdx.x * 4 + wid;
    const int t_base = gwave * TPG;
    const bool active = (t_base < n_tokens);

    if (active) {
        const float4* W4 = reinterpret_cast<const float4*>(W) + lane;
        const float4* h4[TPG];
#pragma unroll
        for (int t = 0; t < TPG; ++t)
            h4[t] = reinterpret_cast<const float4*>(H + (size_t)(t_base + t) * D_MODEL) + lane;

        float acc[TPG * N_EXP];
#pragma unroll
        for (int v = 0; v < TPG * N_EXP; ++v) acc[v] = 0.f;

        float4 hbuf[2][TPG];
#pragma unroll
        for (int t = 0; t < TPG; ++t) hbuf[0][t] = h4[t][0];

#pragma unroll
        for (int j = 0; j < NCHUNK; ++j) {
            const int cur = j & 1, nxt = cur ^ 1;
            // prefetch next H chunk (independent of this iter's FMAs)
            if (j + 1 < NCHUNK) {
#pragma unroll
                for (int t = 0; t < TPG; ++t) hbuf[nxt][t] = h4[t][(j + 1) * 64];
            }
            // W chunk j (L2-hot)
            float4 w[N_EXP];
#pragma unroll
            for (int e = 0; e < N_EXP; ++e)
                w[e] = W4[e * (D_MODEL / 4) + j * 64];
#pragma unroll
            for (int t = 0; t < TPG; ++t) {
                const float4 h = hbuf[cur][t];
#pragma unroll
                for (int e = 0; e < N_EXP; ++e) {
                    float a = acc[t * N_EXP + e];
                    a = fmaf(h.x, w[e].x, a);
                    a = fmaf(h.y, w[e].y, a);
                    a = fmaf(h.z, w[e].z, a);
                    a = fmaf(h.w, w[e].w, a);
                    acc[t * N_EXP + e] = a;
                }
            }
        }

        // Fold-reduce: 32 per-lane partials -> one (token,expert) logit per
        // lane (within each 32-half), summed across all 64 lanes.
        int c = TPG * N_EXP;
#pragma unroll
        for (int k = 0; k < 5; ++k) {
            const int m = 1 << k;
            const int half = c >> 1;
            const bool hi = (lane & m) != 0;
#pragma unroll
            for (int i = 0; i < half; ++i) {
                float keep = hi ? acc[i + half] : acc[i];
                float send = hi ? acc[i] : acc[i + half];
                acc[i] = keep + __shfl_xor(send, m, 64);
            }
            c = half;
        }
        const float logit = acc[0] + __shfl_xor(acc[0], 32, 64);

        // lane (b0..b4) holds value index v = t*8 + e:
        const int v = ((lane & 1) << 4) | (((lane >> 1) & 1) << 3) |
                      (((lane >> 2) & 1) << 2) | (((lane >> 3) & 1) << 1) |
                      ((lane >> 4) & 1);
        if (lane < 32) red[wid][v] = logit;
    }

    __syncthreads();

    if (active && lane < TPG) {
        const int t = t_base + lane;
        if (t < n_tokens) {
            float lg[N_EXP];
#pragma unroll
            for (int e = 0; e < N_EXP; ++e) lg[e] = red[wid][lane * N_EXP + e];

            float m = lg[0];
#pragma unroll
            for (int e = 1; e < N_EXP; ++e) m = fmaxf(m, lg[e]);
            float p[N_EXP], s = 0.f;
#pragma unroll
            for (int e = 0; e < N_EXP; ++e) { p[e] = expf(lg[e] - m); s += p[e]; }
            const float inv = 1.f / s;

            float v1 = -INFINITY, v2 = -INFINITY;
            int i1 = 0, i2 = 0;
#pragma unroll
            for (int e = 0; e < N_EXP; ++e) {
                float vv = lg[e];
                if (vv > v1) { v2 = v1; i2 = i1; v1 = vv; i1 = e; }
                else if (vv > v2) { v2 = vv; i2 = e; }
            }

            *reinterpret_cast<float2*>(&out_idx[2 * t]) = make_float2((float)i1, (float)i2);
            *reinterpret_cast<float2*>(&out_prob[2 * t]) = make_float2(p[i1] * inv, p[i2] * inv);
            atomicAdd(&hist[i1], 1u);
            atomicAdd(&hist[i2], 1u);
        }
    }

    __syncthreads();
    if (tid < N_EXP) atomicAdd(&counts[tid], hist[tid]);
}

__global__ void zero_counts_kernel(unsigned int* counts)
{
    if (threadIdx.x < N_EXP) counts[threadIdx.x] = 0u;
}

__global__ void finalize_kernel(const unsigned int* __restrict__ counts,
                                float* __restrict__ out_aux,
                                float* __restrict__ out_load, int n_tokens)
{
    if (threadIdx.x == 0) {
        const float denom = 1.0f / (float)(n_tokens * TOPK);
        float load[N_EXP];
        float sum = 0.f;
        for (int e = 0; e < N_EXP; ++e) { load[e] = (float)counts[e] * denom; sum += load[e]; }
        const float mean = sum / (float)N_EXP;
        float var = 0.f;
        for (int e = 0; e < N_EXP; ++e) { float d = load[e] - mean; var += d * d; }
        var /= (float)N_EXP;
        const float cv_sq = var / (mean * mean + 1e-9f);
        out_aux[0] = 0.01f * cv_sq;
        for (int e = 0; e < N_EXP; ++e) out_load[e] = load[e];
    }
}

extern "C" void kernel_launch(void* const* d_in, const int* in_sizes, int n_in,
                              void* d_out, int out_size, void* d_ws, size_t ws_size,
                              hipStream_t stream)
{
    const float* H = (const float*)d_in[0];
    const float* W = (const float*)d_in[1];
    const int n_tokens = in_sizes[0] / D_MODEL;  // 16384

    float* out = (float*)d_out;
    float* out_idx = out;
    float* out_prob = out + 2 * (size_t)n_tokens;
    float* out_aux = out + 4 * (size_t)n_tokens;
    float* out_load = out + 4 * (size_t)n_tokens + 1;

    unsigned int* counts = (unsigned int*)d_ws;

    hipLaunchKernelGGL(zero_counts_kernel, dim3(1), dim3(64), 0, stream, counts);

    const int waves_needed = (n_tokens + TPG - 1) / TPG;  // 4096
    const int grid = (waves_needed + 3) / 4;              // 1024
    hipLaunchKernelGGL(moe_gate_kernel, dim3(grid), dim3(256), 0, stream,
                       H, W, out_idx, out_prob, counts, n_tokens);

    hipLaunchKernelGGL(finalize_kernel, dim3(1), dim3(64), 0, stream,
                       counts, out_aux, out_load, n_tokens);
}